// Round 9
// baseline (178.137 us; speedup 1.0000x reference)
//
#include <hip/hip_runtime.h>

typedef __bf16 bf16x8 __attribute__((ext_vector_type(8)));
typedef float f32x4 __attribute__((ext_vector_type(4)));
typedef unsigned short ushort8 __attribute__((ext_vector_type(8)));

__device__ __forceinline__ unsigned short f2bf(float f) {
  unsigned int u = __builtin_bit_cast(unsigned int, f);
  u += 0x7FFFu + ((u >> 16) & 1u);   // RNE
  return (unsigned short)(u >> 16);
}

// COEF[a][du][u] = weight of W-tap u on x-offset du for output phase a
// (interior-exact; borders p==0 / q==0 recomputed by the border path).
__constant__ float COEF[2][3][3] = {
    {{0.25f, 0.00f, 0.00f},
     {0.75f, 0.75f, 0.25f},
     {0.00f, 0.25f, 0.75f}},
    {{0.75f, 0.25f, 0.00f},
     {0.25f, 0.75f, 0.75f},
     {0.00f, 0.00f, 0.25f}}
};

// Pack phase-blended weights into MFMA B-fragment layout, bf16.
// pw[ph][cblk][dv][du][nt][lane][8]; frag (cblk,dv,du,nt): lane l holds
// B[k][oc=nt*16+(l&15)], k=(du*3+dv)*128+cblk*32+(l>>4)*8+j.
__global__ void pack_weights(const float* __restrict__ w, unsigned short* __restrict__ pw) {
  const int kt = blockIdx.x >> 3, nt = blockIdx.x & 7;
  const int l = threadIdx.x;
  const int tap = kt >> 2, cblk = kt & 3;
  const int du = tap / 3, dv = tap - du * 3;
  const int c0 = cblk * 32 + ((l >> 4) << 3);
  const int oc = nt * 16 + (l & 15);
  float accp[4][8];
#pragma unroll
  for (int ph = 0; ph < 4; ++ph)
#pragma unroll
    for (int j = 0; j < 8; ++j) accp[ph][j] = 0.0f;
#pragma unroll
  for (int u = 0; u < 3; ++u)
#pragma unroll
    for (int v = 0; v < 3; ++v) {
      const float ra0 = COEF[0][du][u], ra1 = COEF[1][du][u];
      const float cb0 = COEF[0][dv][v], cb1 = COEF[1][dv][v];
      const float c00 = ra0 * cb0, c01 = ra0 * cb1, c10 = ra1 * cb0, c11 = ra1 * cb1;
#pragma unroll
      for (int j = 0; j < 8; ++j) {
        const float wv = w[((u * 3 + v) * 128 + c0 + j) * 128 + oc];
        accp[0][j] += c00 * wv;
        accp[1][j] += c01 * wv;
        accp[2][j] += c10 * wv;
        accp[3][j] += c11 * wv;
      }
    }
  const int fi = ((cblk * 3 + dv) * 3 + du) * 8 + nt;  // 0..287
#pragma unroll
  for (int ph = 0; ph < 4; ++ph) {
    ushort8 o;
#pragma unroll
    for (int j = 0; j < 8; ++j) o[j] = f2bf(accp[ph][j]);
    *(ushort8*)(pw + (((ph * 288 + fi) * 64 + l) << 3)) = o;
  }
}

// Single fused launch, 256-thread blocks (2 co-resident per CU at 2 waves/SIMD:
// cross-block stage/MFMA overlap). Blocks 0..511 = border fixup; 512..2559 =
// main tiles (out 8x32, 4 waves = phases, wave = 128 pos x 128 oc).
__global__ __launch_bounds__(256, 2) void fused_all(
    const float* __restrict__ x, const unsigned short* __restrict__ pw,
    const float* __restrict__ w, const float* __restrict__ bias,
    float* __restrict__ out) {
  __shared__ __align__(16) char smem[7 * 19 * 256];  // 34,048 B

  const int bid = blockIdx.x;
  const int tid = threadIdx.x;

  if (bid < 512) {
    // ================= BORDER PATH =================
    // 512 blocks = 8 img x 2 type x 32 chunks of 8 border positions.
    const int chunk = bid & 31;
    const int type = (bid >> 5) & 1;  // 0: row p=0 (all q); 1: col q=0 (p>=1)
    const int bi = bid >> 6;
    const int base0 = chunk * 8;
    const float* xb = x + bi * (128 * 128 * 128);

    float* yw = (float*)smem;             // [2][10][128] = 10,240 B
    float* part = (float*)(smem + 10240); // [4][8][128]  = 16,384 B

    // Stage y window (coalesced in c): ws in [0,10) -> t = base0-1+ws.
    {
      const int c = tid & 127;
      const int sub = tid >> 7;  // 0..1
      for (int k = sub; k < 20; k += 2) {
        const int f = k / 10;
        const int ws = k - f * 10;
        const int t = base0 - 1 + ws;
        float val = 0.0f;
        if ((unsigned)t < 256u) {
          const int t0 = t >> 1;
          const float hA0 = (t & 1) ? 0.25f : 0.75f;
          const float hA1 = 1.0f - hA0;
          const float hF0 = f ? 0.25f : 0.75f;
          const float hF1 = 1.0f - hF0;
          const bool ok = (t0 + 1) < 128;
          if (type == 0) {  // fixed x-rows 0,1 ; moving col t
            const float v00 = xb[t0 * 128 + c];
            const float v01 = ok ? xb[(t0 + 1) * 128 + c] : 0.0f;
            const float v10 = xb[(128 + t0) * 128 + c];
            const float v11 = ok ? xb[(128 + t0 + 1) * 128 + c] : 0.0f;
            val = hF0 * (hA0 * v00 + hA1 * v01) + hF1 * (hA0 * v10 + hA1 * v11);
          } else {          // fixed x-cols 0,1 ; moving row t
            const float v00 = xb[(t0 * 128) * 128 + c];
            const float v01 = xb[(t0 * 128 + 1) * 128 + c];
            const float v10 = ok ? xb[((t0 + 1) * 128) * 128 + c] : 0.0f;
            const float v11 = ok ? xb[((t0 + 1) * 128 + 1) * 128 + c] : 0.0f;
            val = hA0 * (hF0 * v00 + hF1 * v01) + hA1 * (hF0 * v10 + hF1 * v11);
          }
        }
        yw[(f * 10 + ws) * 128 + c] = val;
      }
    }
    __syncthreads();

    // Wave wv covers c in [32wv, 32wv+32); lane = 2 oc; 8 pos in regs.
    const int wv = tid >> 6;
    const int oc0 = (tid & 63) * 2;
    const int cbase = wv * 32;

    float acc[8][2] = {};
#pragma unroll 1
    for (int cc = 0; cc < 32; ++cc) {
      float yr[2][10];
#pragma unroll
      for (int f = 0; f < 2; ++f)
#pragma unroll
        for (int ws = 0; ws < 10; ++ws)
          yr[f][ws] = yw[(f * 10 + ws) * 128 + cbase + cc];
#pragma unroll
      for (int tf = 0; tf < 2; ++tf) {
#pragma unroll
        for (int tb = 0; tb < 3; ++tb) {
          const int uu = (type == 0) ? (tf + 1) : tb;
          const int vv = (type == 0) ? tb : (tf + 1);
          const float2 w2 = *(const float2*)(
              w + ((uu * 3 + vv) * 128 + cbase + cc) * 128 + oc0);
#pragma unroll
          for (int pos = 0; pos < 8; ++pos) {
            const float yv = yr[tf][pos + tb];
            acc[pos][0] += yv * w2.x;
            acc[pos][1] += yv * w2.y;
          }
        }
      }
    }

    // Cross-wave reduce via LDS.
#pragma unroll
    for (int pos = 0; pos < 8; ++pos)
      *(float2*)(part + (wv * 8 + pos) * 128 + oc0) = *(float2*)acc[pos];
    __syncthreads();

    const int pos = tid >> 5;        // 0..7
    const int ocp = (tid & 31) * 4;  // float4 over oc
    float4 s = {0.f, 0.f, 0.f, 0.f};
#pragma unroll
    for (int w4i = 0; w4i < 4; ++w4i) {
      const float4 v = *(const float4*)(part + (w4i * 8 + pos) * 128 + ocp);
      s.x += v.x; s.y += v.y; s.z += v.z; s.w += v.w;
    }
    const int posg = base0 + pos;
    if (!(type == 1 && posg == 0)) {
      const int p = (type == 0) ? 0 : posg;
      const int q = (type == 0) ? posg : 0;
      const float4 b4 = *(const float4*)(bias + ocp);
      float4 r;
      r.x = s.x + b4.x; r.y = s.y + b4.y; r.z = s.z + b4.z; r.w = s.w + b4.w;
      *(float4*)(out + bi * (256 * 256 * 128) + (p * 256 + q) * 128 + ocp) = r;
    }
    return;
  }

  // ================= MAIN PATH =================
  // 2048 tiles: out 8 rows x 32 cols x 128 oc. 4 waves = (a,b) phases,
  // wave tile 128 pos x 128 oc: acc[4][8] (128 AGPR). x-tile 7x19x128 bf16.
  char* xlds = smem;
  const int o = bid - 512;
  const int blk = (o & 7) * 256 + (o >> 3);  // bijective XCD swizzle (2048 % 8 == 0)
  const int bimg = blk >> 8;
  const int it = (blk >> 3) & 31;  // 32 row-tiles of 8 out rows
  const int jt = blk & 7;          // 8 col-tiles of 32 out cols
  const int I0 = it * 4, J0 = jt * 16;
  const float* xb = x + bimg * (128 * 128 * 128);

  const int lane = tid & 63;
  const int l15 = lane & 15;
  const int lh = lane >> 4;
  const int wid = tid >> 6;      // 4 waves
  const int a = wid >> 1;        // row phase
  const int b = wid & 1;         // col phase
  const int ph = a * 2 + b;

  const char* pwb = (const char*)pw + ph * 294912 + lane * 16;

#define LOADB(buf, g_, du_)                                           \
  do {                                                                \
    const char* bp_ = pwb + (((g_) * 3 + (du_)) << 13);               \
    _Pragma("unroll") for (int n = 0; n < 8; ++n)                     \
        buf[n] = *(const bf16x8*)(bp_ + n * 1024);                    \
  } while (0)

  bf16x8 bX[8], bY[8];
  LOADB(bX, 0, 0);  // prologue prefetch; completes under the stage barrier

  // ---- Stage x tile: rows I0-1..I0+5, cols J0-1..J0+17 ----
  for (int idx = tid; idx < 7 * 19 * 16; idx += 256) {
    const int cp = idx & 15;
    const int pos = idx >> 4;
    const int xr = pos / 19;
    const int xc = pos - xr * 19;
    const int gi = I0 - 1 + xr;
    const int gj = J0 - 1 + xc;
    ushort8 u8 = {};
    if (((unsigned)gi < 128u) && ((unsigned)gj < 128u)) {
      const float* p = xb + ((gi << 7) + gj) * 128 + (cp << 3);
      const float4 A = *(const float4*)p;
      const float4 Bv = *(const float4*)(p + 4);
      u8[0] = f2bf(A.x); u8[1] = f2bf(A.y); u8[2] = f2bf(A.z); u8[3] = f2bf(A.w);
      u8[4] = f2bf(Bv.x); u8[5] = f2bf(Bv.y); u8[6] = f2bf(Bv.z); u8[7] = f2bf(Bv.w);
    }
    int byte = (pos << 8) + (cp << 4);
    byte ^= (pos & 7) << 4;  // bank swizzle (write side)
    *(ushort8*)(xlds + byte) = u8;
  }
  __syncthreads();

  f32x4 acc[4][8] = {};
  const int colpart = l15 + b;

#define AREAD(rr, dv_)                                                \
  do {                                                                \
    const int posa = (a + (rr)) * 19 + colpart + (dv_);               \
    int byte_ = (posa << 8) + kbyte;                                  \
    byte_ ^= (posa & 7) << 4;  /* read-side swizzle */                \
    af[rr] = *(const bf16x8*)(xlds + byte_);                          \
  } while (0)

#define MFMAS(du_, buf)                                               \
  do {                                                                \
    __builtin_amdgcn_s_setprio(1);                                    \
    _Pragma("unroll") for (int m = 0; m < 4; ++m)                     \
        _Pragma("unroll") for (int n = 0; n < 8; ++n)                 \
            acc[m][n] = __builtin_amdgcn_mfma_f32_16x16x32_bf16(      \
                af[(du_) + m], buf[n], acc[m][n], 0, 0, 0);           \
    __builtin_amdgcn_s_setprio(0);                                    \
  } while (0)

#pragma unroll 1
  for (int g = 0; g < 12; g += 2) {
    // ---- group g (du-blocks use bX, bY, bX) ----
    {
      const int cblk = (g * 11) >> 5;  // g/3
      const int dv = g - cblk * 3;
      const int kbyte = (cblk * 4 + lh) << 4;
      bf16x8 af[6];
      AREAD(0, dv); AREAD(1, dv); AREAD(2, dv);
      AREAD(3, dv); AREAD(4, dv); AREAD(5, dv);
      LOADB(bY, g, 1);
      MFMAS(0, bX);
      LOADB(bX, g, 2);
      MFMAS(1, bY);
      LOADB(bY, g + 1, 0);
      MFMAS(2, bX);
    }
    // ---- group g+1 (du-blocks use bY, bX, bY) ----
    {
      const int g1 = g + 1;
      const int cblk = (g1 * 11) >> 5;
      const int dv = g1 - cblk * 3;
      const int kbyte = (cblk * 4 + lh) << 4;
      bf16x8 af[6];
      AREAD(0, dv); AREAD(1, dv); AREAD(2, dv);
      AREAD(3, dv); AREAD(4, dv); AREAD(5, dv);
      LOADB(bX, g1, 1);
      MFMAS(0, bY);
      LOADB(bY, g1, 2);
      MFMAS(1, bX);
      {
        const int gn = (g + 2 < 12) ? (g + 2) : 11;  // clamp: keep in-bounds
        LOADB(bX, gn, 0);
      }
      MFMAS(2, bY);
    }
  }
#undef AREAD
#undef MFMAS
#undef LOADB

  // ---- Epilogue: C/D col=lane&15 (oc), row m=lh*4+reg (out-col index);
  //      border stores (p==0 or q==0) owned by border path ----
  float bv[8];
#pragma unroll
  for (int n = 0; n < 8; ++n) bv[n] = bias[n * 16 + l15];
  float* ob = out + bimg * (256 * 256 * 128) + l15;
#pragma unroll
  for (int m = 0; m < 4; ++m) {
    const int p = it * 8 + 2 * m + a;
    if (p == 0) continue;  // wave-uniform
#pragma unroll
    for (int jr = 0; jr < 4; ++jr) {
      const int q = jt * 32 + 2 * (lh * 4 + jr) + b;
      if (q == 0) continue;  // diverges only at jt==0,b==0,jr==0 for lh==0
      float* orow = ob + (p * 256 + q) * 128;
#pragma unroll
      for (int n = 0; n < 8; ++n) orow[n * 16] = acc[m][n][jr] + bv[n];
    }
  }
}

extern "C" void kernel_launch(void* const* d_in, const int* in_sizes, int n_in,
                              void* d_out, int out_size, void* d_ws, size_t ws_size,
                              hipStream_t stream) {
  const float* x = (const float*)d_in[0];
  const float* w = (const float*)d_in[1];
  const float* bias = (const float*)d_in[2];
  float* out = (float*)d_out;
  unsigned short* pw = (unsigned short*)d_ws;  // 1,179,648 B used

  pack_weights<<<dim3(288), dim3(64), 0, stream>>>(w, pw);
  fused_all<<<dim3(2560), dim3(256), 0, stream>>>(x, pw, w, bias, out);
}